// Round 6
// baseline (16285.072 us; speedup 1.0000x reference)
//
#include <hip/hip_runtime.h>

#define R     8192
#define C1    8213
#define C2    8192
#define CPB   8224      // K row stride in BYTES (fp8); multiple of 16
#define CPF   8224      // part/v row length in floats
#define NCHK  514       // 16-byte chunks per K row
#define NBLK  512       // persistent grid size (2 blocks/CU guaranteed by launch_bounds)
#define RPB   16        // rows per block (R / NBLK)

typedef float f32x2 __attribute__((ext_vector_type(2)));

__device__ __forceinline__ void fp8x16_to_f(const int4 w, float f[16]) {
    f32x2 p;
    p = __builtin_amdgcn_cvt_pk_f32_fp8(w.x, false); f[0]  = p.x; f[1]  = p.y;
    p = __builtin_amdgcn_cvt_pk_f32_fp8(w.x, true);  f[2]  = p.x; f[3]  = p.y;
    p = __builtin_amdgcn_cvt_pk_f32_fp8(w.y, false); f[4]  = p.x; f[5]  = p.y;
    p = __builtin_amdgcn_cvt_pk_f32_fp8(w.y, true);  f[6]  = p.x; f[7]  = p.y;
    p = __builtin_amdgcn_cvt_pk_f32_fp8(w.z, false); f[8]  = p.x; f[9]  = p.y;
    p = __builtin_amdgcn_cvt_pk_f32_fp8(w.z, true);  f[10] = p.x; f[11] = p.y;
    p = __builtin_amdgcn_cvt_pk_f32_fp8(w.w, false); f[12] = p.x; f[13] = p.y;
    p = __builtin_amdgcn_cvt_pk_f32_fp8(w.w, true);  f[14] = p.x; f[15] = p.y;
}

__device__ __forceinline__ float fp8_to_f(int byte) {
    f32x2 p = __builtin_amdgcn_cvt_pk_f32_fp8(byte & 0xff, false);
    return p.x;
}

__device__ __forceinline__ float gm_label(float sc, int lab) {
    if (lab == 0) return fmaxf(-0.02f - sc, 0.0f) + fmaxf(sc, 0.0f);
    if (lab == 3) return fmaxf(0.09f + sc, 0.0f);
    return fmaxf(0.05f + sc, 0.0f) + fmaxf(-0.09f - sc, 0.0f); // labels 1|2
}

__device__ __forceinline__ float kval(float gm) {
    // K = exp(-M/REG), M = exp(-GM), REG = -0.2  ->  exp(5*exp(-GM)); hw exp
    return __expf(5.0f * __expf(-gm));
}

// ---- build kernels (unchanged from R5): fp8 packed dword stores, rows zero-padded ----

__global__ __launch_bounds__(256) void build_k1(const float* __restrict__ dist,
                                                const int* __restrict__ lab,
                                                unsigned char* __restrict__ K) {
    int row = blockIdx.y;
    int j0 = (blockIdx.x * 256 + threadIdx.x) * 4;
    if (j0 >= CPB) return;
    size_t ib = (size_t)row * C1;
    float d0 = dist[ib];
    float val[4];
#pragma unroll
    for (int k = 0; k < 4; ++k) {
        int j = j0 + k;
        val[k] = 0.0f;
        if (j < C1) {
            float g = gm_label(dist[ib + j] - d0, lab[ib + j]);
            val[k] = kval(g);
        }
    }
    int p = 0;
    p = __builtin_amdgcn_cvt_pk_fp8_f32(val[0], val[1], p, false);
    p = __builtin_amdgcn_cvt_pk_fp8_f32(val[2], val[3], p, true);
    *reinterpret_cast<int*>(K + (size_t)row * CPB + j0) = p;
}

__global__ __launch_bounds__(256) void diag_k(const float* __restrict__ dist,
                                              float* __restrict__ dcol) {
    int j = blockIdx.x * 256 + threadIdx.x;
    if (j < R) dcol[j] = dist[(size_t)j * C1 + 21 + j];
}

__global__ __launch_bounds__(256) void build_k2(const float* __restrict__ dist,
                                                const float* __restrict__ dcol,
                                                unsigned char* __restrict__ K) {
    int row = blockIdx.y;
    int j0 = (blockIdx.x * 256 + threadIdx.x) * 4;
    if (j0 >= CPB) return;
    size_t ib = (size_t)row * C1 + 21;
    float val[4];
#pragma unroll
    for (int k = 0; k < 4; ++k) {
        int j = j0 + k;
        val[k] = 0.0f;
        if (j < C2) {
            float s = dist[ib + j] - dcol[j];
            float g = (j == row) ? 0.0f : fmaxf(0.09f + s, 0.0f);
            val[k] = kval(g);
        }
    }
    int p = 0;
    p = __builtin_amdgcn_cvt_pk_fp8_f32(val[0], val[1], p, false);
    p = __builtin_amdgcn_cvt_pk_fp8_f32(val[2], val[3], p, true);
    *reinterpret_cast<int*>(K + (size_t)row * CPB + j0) = p;
}

__global__ void zero_bar(unsigned* __restrict__ bar) {
    if (threadIdx.x == 0) *bar = 0u;
}

// ---- software grid barrier: monotonic counter, agent-scope release/acquire ----
__device__ __forceinline__ unsigned gridbar(unsigned* bar, unsigned target) {
    __syncthreads();
    if (threadIdx.x == 0) {
        __hip_atomic_fetch_add(bar, 1u, __ATOMIC_ACQ_REL, __HIP_MEMORY_SCOPE_AGENT);
        while (__hip_atomic_load(bar, __ATOMIC_ACQUIRE, __HIP_MEMORY_SCOPE_AGENT) < target)
            __builtin_amdgcn_s_sleep(2);
    }
    __syncthreads();
    return target + NBLK;
}

// ---- persistent Sinkhorn phase: 50 iterations, 2 grid barriers each.
//      Block owns 16 rows; u lives in LDS only. Per 4-row group: wave w dots
//      row (vs v) -> uls; sync; all threads accumulate those 4 rows into column
//      partials (second read of the rows is XCD-L2-hot). Then part -> barrier ->
//      v-compute (block sums its 16-col slice over all 512 splits) -> barrier. ----
__global__ __launch_bounds__(256, 2) void sink_k(const unsigned char* __restrict__ K,
                                                 float* __restrict__ part,
                                                 float* __restrict__ v,
                                                 unsigned* __restrict__ bar,
                                                 int C, float aval, float bval) {
    __shared__ float uls[RPB];
    __shared__ float red[16][16];
    const int tx = threadIdx.x, b = blockIdx.x;
    const int lane = tx & 63, wv = tx >> 6;
    const int r0 = b * RPB;
    const bool tail = tx < 2;
    const int4* Kb = reinterpret_cast<const int4*>(K);
    unsigned tgt = NBLK;

    for (int t = 0; t < 50; ++t) {
        if (t == 0) {
            if (tx < RPB) uls[tx] = aval;
            __syncthreads();
        }
        float acc0[16], acc1[16], acct[16];
#pragma unroll
        for (int k = 0; k < 16; ++k) { acc0[k] = 0.f; acc1[k] = 0.f; acct[k] = 0.f; }
        const float4* v4 = reinterpret_cast<const float4*>(v);

        for (int rg = 0; rg < RPB / 4; ++rg) {
            if (t > 0) {
                // wave wv dots row r0+rg*4+wv against v
                int row = r0 + rg * 4 + wv;
                const int4* Kr = Kb + (size_t)row * NCHK;
                float dot = 0.0f;
#pragma unroll
                for (int s = 0; s < 8; ++s) {
                    int ch = s * 64 + lane;
                    float f[16]; fp8x16_to_f(Kr[ch], f);
#pragma unroll
                    for (int q = 0; q < 4; ++q) {
                        float4 w = v4[ch * 4 + q];
                        dot = fmaf(f[q * 4 + 0], w.x, dot);
                        dot = fmaf(f[q * 4 + 1], w.y, dot);
                        dot = fmaf(f[q * 4 + 2], w.z, dot);
                        dot = fmaf(f[q * 4 + 3], w.w, dot);
                    }
                }
                if (lane < 2) {
                    int ch = 512 + lane;
                    float f[16]; fp8x16_to_f(Kr[ch], f);
#pragma unroll
                    for (int q = 0; q < 4; ++q) {
                        float4 w = v4[ch * 4 + q];
                        dot = fmaf(f[q * 4 + 0], w.x, dot);
                        dot = fmaf(f[q * 4 + 1], w.y, dot);
                        dot = fmaf(f[q * 4 + 2], w.z, dot);
                        dot = fmaf(f[q * 4 + 3], w.w, dot);
                    }
                }
#pragma unroll
                for (int off = 32; off; off >>= 1) dot += __shfl_down(dot, off, 64);
                if (lane == 0) uls[rg * 4 + wv] = aval / dot;
                __syncthreads();
            }
            // accumulate the group's 4 rows into column partials
#pragma unroll
            for (int r = 0; r < 4; ++r) {
                int row = r0 + rg * 4 + r;
                float uu = uls[rg * 4 + r];
                const int4* Kr = Kb + (size_t)row * NCHK;
                {
                    float f[16]; fp8x16_to_f(Kr[tx], f);
#pragma unroll
                    for (int k = 0; k < 16; ++k) acc0[k] = fmaf(f[k], uu, acc0[k]);
                }
                {
                    float f[16]; fp8x16_to_f(Kr[256 + tx], f);
#pragma unroll
                    for (int k = 0; k < 16; ++k) acc1[k] = fmaf(f[k], uu, acc1[k]);
                }
                if (tail) {
                    float f[16]; fp8x16_to_f(Kr[512 + tx], f);
#pragma unroll
                    for (int k = 0; k < 16; ++k) acct[k] = fmaf(f[k], uu, acct[k]);
                }
            }
        }
        // write this block's column-partial row
        float4* prow = reinterpret_cast<float4*>(part + (size_t)b * CPF);
#pragma unroll
        for (int q = 0; q < 4; ++q) {
            prow[tx * 4 + q] = make_float4(acc0[q * 4], acc0[q * 4 + 1],
                                           acc0[q * 4 + 2], acc0[q * 4 + 3]);
            prow[(256 + tx) * 4 + q] = make_float4(acc1[q * 4], acc1[q * 4 + 1],
                                                   acc1[q * 4 + 2], acc1[q * 4 + 3]);
        }
        if (tail) {
#pragma unroll
            for (int q = 0; q < 4; ++q)
                prow[(512 + tx) * 4 + q] = make_float4(acct[q * 4], acct[q * 4 + 1],
                                                       acct[q * 4 + 2], acct[q * 4 + 3]);
        }

        tgt = gridbar(bar, tgt);

        // v-compute: block handles 16-col groups g = b (+ g = b+512 for b<2)
        for (int g = b; g < 514; g += NBLK) {
            int c16 = tx & 15, sq = tx >> 4;
            int j = g * 16 + c16;
            float s = 0.0f;
            for (int k = 0; k < 32; ++k)
                s += part[(size_t)(sq * 32 + k) * CPF + j];
            red[sq][c16] = s;
            __syncthreads();
            if (tx < 16) {
                float tot = 0.0f;
#pragma unroll
                for (int q = 0; q < 16; ++q) tot += red[q][tx];
                int jj = g * 16 + tx;
                v[jj] = (jj < C) ? bval / tot : 0.0f;
            }
            __syncthreads();
        }

        if (t < 49) tgt = gridbar(bar, tgt);
    }
}

// ---- loss reductions (unchanged from R5) ----

__device__ __forceinline__ float2 block_reduce_2(float x, float y, float* sb) {
#pragma unroll
    for (int off = 32; off; off >>= 1) {
        x += __shfl_down(x, off, 64);
        y += __shfl_down(y, off, 64);
    }
    if ((threadIdx.x & 63) == 0) {
        int w = threadIdx.x >> 6;
        sb[w] = x; sb[4 + w] = y;
    }
    __syncthreads();
    float2 r;
    r.x = sb[0] + sb[1] + sb[2] + sb[3];
    r.y = sb[4] + sb[5] + sb[6] + sb[7];
    __syncthreads();
    return r;
}

__global__ __launch_bounds__(256) void loss1_k(const unsigned char* __restrict__ K,
                                               const float* __restrict__ v,
                                               const float* __restrict__ dist,
                                               const int* __restrict__ lab,
                                               float* __restrict__ ratio) {
    __shared__ float sb[8];
    int i = blockIdx.x;
    size_t ib = (size_t)i * C1;
    float d0 = dist[ib];
    const unsigned char* Kr = K + (size_t)i * CPB;
    float num = 0, den = 0;
    for (int j0 = threadIdx.x * 4; j0 < C1; j0 += 1024) {
        int p = *reinterpret_cast<const int*>(Kr + j0);
#pragma unroll
        for (int k = 0; k < 4; ++k) {
            int j = j0 + k;
            int jc = (j < C1) ? j : (C1 - 1);
            float kv = fp8_to_f(p >> (k * 8)) * v[jc];   // K pad = 0 -> kv = 0 beyond C1
            float g = gm_label(dist[ib + jc] - d0, lab[ib + jc]);
            den += kv;
            num = fmaf(g, kv, num);
        }
    }
    float2 r = block_reduce_2(num, den, sb);
    if (threadIdx.x == 0) ratio[i] = r.x / r.y;
}

__global__ __launch_bounds__(256) void loss2_k(const unsigned char* __restrict__ K,
                                               const float* __restrict__ v,
                                               const float* __restrict__ dist,
                                               const float* __restrict__ dcol,
                                               float* __restrict__ ratio) {
    __shared__ float sb[8];
    int i = blockIdx.x;
    const unsigned char* Kr = K + (size_t)i * CPB;
    const float* Dr = dist + (size_t)i * C1 + 21;
    float num = 0, den = 0;
    for (int j0 = threadIdx.x * 4; j0 < C2; j0 += 1024) {
        int p = *reinterpret_cast<const int*>(Kr + j0);
#pragma unroll
        for (int k = 0; k < 4; ++k) {
            int j = j0 + k;
            if (j == i) continue;
            float kv = fp8_to_f(p >> (k * 8)) * v[j];
            float h = fmaxf(0.09f + Dr[j] - dcol[j], 0.0f);
            den += kv;
            num = fmaf(h, kv, num);
        }
    }
    float2 r = block_reduce_2(num, den, sb);
    if (threadIdx.x == 0) ratio[i] = r.x / r.y;
}

__global__ __launch_bounds__(256) void final_k(const float* __restrict__ r1,
                                               const float* __restrict__ r2,
                                               float* __restrict__ out) {
    __shared__ float sb[8];
    float s1 = 0, s2 = 0;
    for (int i = threadIdx.x; i < R; i += 256) { s1 += r1[i]; s2 += r2[i]; }
    float2 t = block_reduce_2(s1, s2, sb);
    if (threadIdx.x == 0)
        out[0] = t.x / ((float)R * (float)C1) + t.y / ((float)R * (float)C2);
}

extern "C" void kernel_launch(void* const* d_in, const int* in_sizes, int n_in,
                              void* d_out, int out_size, void* d_ws, size_t ws_size,
                              hipStream_t stream) {
    const float* dist = (const float*)d_in[0];
    const int* lab = (const int*)d_in[1];
    float* out = (float*)d_out;
    char* ws = (char*)d_ws;

    size_t need = (size_t)R * CPB                        // K (fp8)
                + (size_t)NBLK * CPF * sizeof(float)     // part
                + (size_t)CPF * sizeof(float)            // v
                + 3 * (size_t)R * sizeof(float)          // dcol, rat1, rat2
                + 128;                                   // barrier counter
    if (ws_size < need) return;

    size_t off = 0;
    unsigned char* K = (unsigned char*)(ws + off); off += (size_t)R * CPB;
    float* part = (float*)(ws + off);  off += (size_t)NBLK * CPF * sizeof(float);
    float* v = (float*)(ws + off);     off += (size_t)CPF * sizeof(float);
    float* dcol = (float*)(ws + off);  off += (size_t)R * sizeof(float);
    float* rat1 = (float*)(ws + off);  off += (size_t)R * sizeof(float);
    float* rat2 = (float*)(ws + off);  off += (size_t)R * sizeof(float);
    unsigned* bar = (unsigned*)(ws + off); off += 128;

    float aval = 1.0f / (float)R;
    int gb = (CPB / 4 + 255) / 256;  // 9 blocks per row

    // ---- phase 1 ----
    build_k1<<<dim3(gb, R), 256, 0, stream>>>(dist, lab, K);
    zero_bar<<<dim3(1), 64, 0, stream>>>(bar);
    sink_k<<<dim3(NBLK), 256, 0, stream>>>(K, part, v, bar, C1, aval, 1.0f / (float)C1);
    loss1_k<<<dim3(R), 256, 0, stream>>>(K, v, dist, lab, rat1);

    // ---- phase 2 (reuses K buffer) ----
    diag_k<<<dim3(R / 256), 256, 0, stream>>>(dist, dcol);
    build_k2<<<dim3(gb, R), 256, 0, stream>>>(dist, dcol, K);
    zero_bar<<<dim3(1), 64, 0, stream>>>(bar);
    sink_k<<<dim3(NBLK), 256, 0, stream>>>(K, part, v, bar, C2, aval, 1.0f / (float)C2);
    loss2_k<<<dim3(R), 256, 0, stream>>>(K, v, dist, dcol, rat2);

    final_k<<<dim3(1), 256, 0, stream>>>(rat1, rat2, out);
}

// Round 7
// 12735.066 us; speedup vs baseline: 1.2788x; 1.2788x over previous
//
#include <hip/hip_runtime.h>

#define R     8192
#define C1    8213
#define C2    8192
#define CPB   8224      // K row stride in BYTES (fp8); multiple of 16
#define CPF   8224      // part/v row length in floats
#define NCHK  514       // 16-byte chunks per K row
#define NBLK  512       // persistent grid size (2 blocks/CU by capacity)
#define TPB   512
#define RPB   16        // rows per block (R / NBLK)

typedef float f32x2 __attribute__((ext_vector_type(2)));

__device__ __forceinline__ void fp8x16_to_f(const int4 w, float f[16]) {
    f32x2 p;
    p = __builtin_amdgcn_cvt_pk_f32_fp8(w.x, false); f[0]  = p.x; f[1]  = p.y;
    p = __builtin_amdgcn_cvt_pk_f32_fp8(w.x, true);  f[2]  = p.x; f[3]  = p.y;
    p = __builtin_amdgcn_cvt_pk_f32_fp8(w.y, false); f[4]  = p.x; f[5]  = p.y;
    p = __builtin_amdgcn_cvt_pk_f32_fp8(w.y, true);  f[6]  = p.x; f[7]  = p.y;
    p = __builtin_amdgcn_cvt_pk_f32_fp8(w.z, false); f[8]  = p.x; f[9]  = p.y;
    p = __builtin_amdgcn_cvt_pk_f32_fp8(w.z, true);  f[10] = p.x; f[11] = p.y;
    p = __builtin_amdgcn_cvt_pk_f32_fp8(w.w, false); f[12] = p.x; f[13] = p.y;
    p = __builtin_amdgcn_cvt_pk_f32_fp8(w.w, true);  f[14] = p.x; f[15] = p.y;
}

__device__ __forceinline__ float fp8_to_f(int byte) {
    f32x2 p = __builtin_amdgcn_cvt_pk_f32_fp8(byte & 0xff, false);
    return p.x;
}

__device__ __forceinline__ float gm_label(float sc, int lab) {
    if (lab == 0) return fmaxf(-0.02f - sc, 0.0f) + fmaxf(sc, 0.0f);
    if (lab == 3) return fmaxf(0.09f + sc, 0.0f);
    return fmaxf(0.05f + sc, 0.0f) + fmaxf(-0.09f - sc, 0.0f); // labels 1|2
}

__device__ __forceinline__ float kval(float gm) {
    // K = exp(-M/REG), M = exp(-GM), REG = -0.2  ->  exp(5*exp(-GM)); hw exp
    return __expf(5.0f * __expf(-gm));
}

__device__ __forceinline__ float dot16(const float f[16], const float w[16]) {
    float d = 0.0f;
#pragma unroll
    for (int k = 0; k < 16; ++k) d = fmaf(f[k], w[k], d);
    return d;
}

// ---- build kernels (R5-proven) ----

__global__ __launch_bounds__(256) void build_k1(const float* __restrict__ dist,
                                                const int* __restrict__ lab,
                                                unsigned char* __restrict__ K) {
    int row = blockIdx.y;
    int j0 = (blockIdx.x * 256 + threadIdx.x) * 4;
    if (j0 >= CPB) return;
    size_t ib = (size_t)row * C1;
    float d0 = dist[ib];
    float val[4];
#pragma unroll
    for (int k = 0; k < 4; ++k) {
        int j = j0 + k;
        val[k] = 0.0f;
        if (j < C1) {
            float g = gm_label(dist[ib + j] - d0, lab[ib + j]);
            val[k] = kval(g);
        }
    }
    int p = 0;
    p = __builtin_amdgcn_cvt_pk_fp8_f32(val[0], val[1], p, false);
    p = __builtin_amdgcn_cvt_pk_fp8_f32(val[2], val[3], p, true);
    *reinterpret_cast<int*>(K + (size_t)row * CPB + j0) = p;
}

__global__ __launch_bounds__(256) void diag_k(const float* __restrict__ dist,
                                              float* __restrict__ dcol) {
    int j = blockIdx.x * 256 + threadIdx.x;
    if (j < R) dcol[j] = dist[(size_t)j * C1 + 21 + j];
}

__global__ __launch_bounds__(256) void build_k2(const float* __restrict__ dist,
                                                const float* __restrict__ dcol,
                                                unsigned char* __restrict__ K) {
    int row = blockIdx.y;
    int j0 = (blockIdx.x * 256 + threadIdx.x) * 4;
    if (j0 >= CPB) return;
    size_t ib = (size_t)row * C1 + 21;
    float val[4];
#pragma unroll
    for (int k = 0; k < 4; ++k) {
        int j = j0 + k;
        val[k] = 0.0f;
        if (j < C2) {
            float s = dist[ib + j] - dcol[j];
            float g = (j == row) ? 0.0f : fmaxf(0.09f + s, 0.0f);
            val[k] = kval(g);
        }
    }
    int p = 0;
    p = __builtin_amdgcn_cvt_pk_fp8_f32(val[0], val[1], p, false);
    p = __builtin_amdgcn_cvt_pk_fp8_f32(val[2], val[3], p, true);
    *reinterpret_cast<int*>(K + (size_t)row * CPB + j0) = p;
}

// ---- barrier plumbing: 8 arrival counters + 64 epoch broadcast lines (256B apart) ----

__global__ void zero_bar(unsigned* __restrict__ bar) {
    int i = threadIdx.x;
    if (i < 72) bar[i << 6] = 0u;
}

__device__ __forceinline__ void gridbar(unsigned* __restrict__ ctr,
                                        unsigned* __restrict__ ep,
                                        int b, unsigned k) {
    __syncthreads();
    if (threadIdx.x == 0) {
        __hip_atomic_fetch_add(&ctr[(b & 7) << 6], 1u, __ATOMIC_RELEASE,
                               __HIP_MEMORY_SCOPE_AGENT);
        if (b == 0) {
            const unsigned target = k * NBLK;
            for (;;) {
                unsigned s = 0;
#pragma unroll
                for (int i = 0; i < 8; ++i)
                    s += __hip_atomic_load(&ctr[i << 6], __ATOMIC_ACQUIRE,
                                           __HIP_MEMORY_SCOPE_AGENT);
                if (s >= target) break;
                __builtin_amdgcn_s_sleep(1);
            }
#pragma unroll 8
            for (int i = 0; i < 64; ++i)
                __hip_atomic_store(&ep[i << 6], k, __ATOMIC_RELEASE,
                                   __HIP_MEMORY_SCOPE_AGENT);
        } else {
            unsigned* my = &ep[(b & 63) << 6];
            while (__hip_atomic_load(my, __ATOMIC_RELAXED,
                                     __HIP_MEMORY_SCOPE_AGENT) < k)
                __builtin_amdgcn_s_sleep(2);
            (void)__hip_atomic_load(my, __ATOMIC_ACQUIRE, __HIP_MEMORY_SCOPE_AGENT);
        }
    }
    __syncthreads();
}

// ---- persistent Sinkhorn: 50 iters, 2 scalable grid barriers each (99 total).
//      Thread owns chunk c=tx (cols 16c..16c+15); threads 0,1 also own tail chunks.
//      Per 2-row tile: sweep1 dot rows vs reg-resident v-slice -> LDS reduce -> u;
//      sweep2 re-read (L2-hot) scaled into col accumulators. ----
__global__ __launch_bounds__(TPB, 4) void sink_k(const unsigned char* __restrict__ K,
                                                 float* __restrict__ part,
                                                 float* __restrict__ v,
                                                 unsigned* __restrict__ ctr,
                                                 unsigned* __restrict__ ep,
                                                 int C, float aval, float bval) {
    __shared__ float pd[2][TPB];
    __shared__ float uls[RPB];
    const int tx = threadIdx.x, b = blockIdx.x;
    const int lane = tx & 63, wv = tx >> 6;
    const int r0 = b * RPB;
    const bool tail = tx < 2;
    const int ctail = 512 + tx;
    const int4* Kb = reinterpret_cast<const int4*>(K);
    unsigned bark = 0;

    for (int t = 0; t < 50; ++t) {
        float acc[16], acct[16];
#pragma unroll
        for (int k = 0; k < 16; ++k) { acc[k] = 0.0f; acct[k] = 0.0f; }

        if (t == 0) {
            // u uniform: plain col accumulation
            for (int r = 0; r < RPB; ++r) {
                float f[16];
                fp8x16_to_f(Kb[(size_t)(r0 + r) * NCHK + tx], f);
#pragma unroll
                for (int k = 0; k < 16; ++k) acc[k] = fmaf(f[k], aval, acc[k]);
                if (tail) {
                    float g[16];
                    fp8x16_to_f(Kb[(size_t)(r0 + r) * NCHK + ctail], g);
#pragma unroll
                    for (int k = 0; k < 16; ++k) acct[k] = fmaf(g[k], aval, acct[k]);
                }
            }
        } else {
            const float4* v4 = reinterpret_cast<const float4*>(v);
            float w[16];
            {
                float4 a0 = v4[tx * 4], a1 = v4[tx * 4 + 1];
                float4 a2 = v4[tx * 4 + 2], a3 = v4[tx * 4 + 3];
                w[0] = a0.x; w[1] = a0.y; w[2]  = a0.z; w[3]  = a0.w;
                w[4] = a1.x; w[5] = a1.y; w[6]  = a1.z; w[7]  = a1.w;
                w[8] = a2.x; w[9] = a2.y; w[10] = a2.z; w[11] = a2.w;
                w[12] = a3.x; w[13] = a3.y; w[14] = a3.z; w[15] = a3.w;
            }
            for (int j = 0; j < RPB / 2; ++j) {
                int ra = r0 + 2 * j, rb = ra + 1;
                float f[16];
                // sweep1: dots
                fp8x16_to_f(Kb[(size_t)ra * NCHK + tx], f);
                float p0 = dot16(f, w);
                fp8x16_to_f(Kb[(size_t)rb * NCHK + tx], f);
                float p1 = dot16(f, w);
                if (tail) {
                    float wt[16];
                    float4 a0 = v4[ctail * 4], a1 = v4[ctail * 4 + 1];
                    float4 a2 = v4[ctail * 4 + 2], a3 = v4[ctail * 4 + 3];
                    wt[0] = a0.x; wt[1] = a0.y; wt[2]  = a0.z; wt[3]  = a0.w;
                    wt[4] = a1.x; wt[5] = a1.y; wt[6]  = a1.z; wt[7]  = a1.w;
                    wt[8] = a2.x; wt[9] = a2.y; wt[10] = a2.z; wt[11] = a2.w;
                    wt[12] = a3.x; wt[13] = a3.y; wt[14] = a3.z; wt[15] = a3.w;
                    fp8x16_to_f(Kb[(size_t)ra * NCHK + ctail], f);
                    p0 += dot16(f, wt);
                    fp8x16_to_f(Kb[(size_t)rb * NCHK + ctail], f);
                    p1 += dot16(f, wt);
                }
                pd[0][tx] = p0;
                pd[1][tx] = p1;
                __syncthreads();
                if (wv < 2) {
                    float s = 0.0f;
#pragma unroll
                    for (int q = 0; q < 8; ++q) s += pd[wv][lane + q * 64];
#pragma unroll
                    for (int off = 32; off; off >>= 1) s += __shfl_down(s, off, 64);
                    if (lane == 0) uls[2 * j + wv] = aval / s;
                }
                __syncthreads();
                // sweep2: scaled accumulation (rows are L2-hot)
                float u0 = uls[2 * j], u1 = uls[2 * j + 1];
                fp8x16_to_f(Kb[(size_t)ra * NCHK + tx], f);
#pragma unroll
                for (int k = 0; k < 16; ++k) acc[k] = fmaf(u0, f[k], acc[k]);
                fp8x16_to_f(Kb[(size_t)rb * NCHK + tx], f);
#pragma unroll
                for (int k = 0; k < 16; ++k) acc[k] = fmaf(u1, f[k], acc[k]);
                if (tail) {
                    fp8x16_to_f(Kb[(size_t)ra * NCHK + ctail], f);
#pragma unroll
                    for (int k = 0; k < 16; ++k) acct[k] = fmaf(u0, f[k], acct[k]);
                    fp8x16_to_f(Kb[(size_t)rb * NCHK + ctail], f);
#pragma unroll
                    for (int k = 0; k < 16; ++k) acct[k] = fmaf(u1, f[k], acct[k]);
                }
            }
        }

        // write this block's column-partial row
        float4* prow = reinterpret_cast<float4*>(part + (size_t)b * CPF);
#pragma unroll
        for (int q = 0; q < 4; ++q)
            prow[tx * 4 + q] = make_float4(acc[q * 4], acc[q * 4 + 1],
                                           acc[q * 4 + 2], acc[q * 4 + 3]);
        if (tail) {
#pragma unroll
            for (int q = 0; q < 4; ++q)
                prow[ctail * 4 + q] = make_float4(acct[q * 4], acct[q * 4 + 1],
                                                  acct[q * 4 + 2], acct[q * 4 + 3]);
        }

        gridbar(ctr, ep, b, ++bark);

        // v-compute: 129 blocks, 64 coalesced cols each, LDS-reduced over 512 splits
        if (b < 129) {
            float* red = &pd[0][0];   // reuse: need 8*72 = 576 <= 1024 floats
            int c63 = tx & 63, seg = tx >> 6;
            int col = b * 64 + c63;
            float s0 = 0.0f, s1 = 0.0f;
            if (col < CPF) {
                const float* p = part + col;
                for (int k = 0; k < 64; k += 2) {
                    s0 += p[(size_t)(seg * 64 + k) * CPF];
                    s1 += p[(size_t)(seg * 64 + k + 1) * CPF];
                }
            }
            red[seg * 72 + c63] = s0 + s1;
            __syncthreads();
            if (tx < 64) {
                int jj = b * 64 + tx;
                if (jj < CPF) {
                    float tot = 0.0f;
#pragma unroll
                    for (int q = 0; q < 8; ++q) tot += red[q * 72 + tx];
                    v[jj] = (jj < C) ? bval / tot : 0.0f;
                }
            }
            __syncthreads();
        }

        if (t < 49) gridbar(ctr, ep, b, ++bark);
    }
}

// ---- loss reductions (R5-proven) ----

__device__ __forceinline__ float2 block_reduce_2(float x, float y, float* sb) {
#pragma unroll
    for (int off = 32; off; off >>= 1) {
        x += __shfl_down(x, off, 64);
        y += __shfl_down(y, off, 64);
    }
    if ((threadIdx.x & 63) == 0) {
        int w = threadIdx.x >> 6;
        sb[w] = x; sb[4 + w] = y;
    }
    __syncthreads();
    float2 r;
    r.x = sb[0] + sb[1] + sb[2] + sb[3];
    r.y = sb[4] + sb[5] + sb[6] + sb[7];
    __syncthreads();
    return r;
}

__global__ __launch_bounds__(256) void loss1_k(const unsigned char* __restrict__ K,
                                               const float* __restrict__ v,
                                               const float* __restrict__ dist,
                                               const int* __restrict__ lab,
                                               float* __restrict__ ratio) {
    __shared__ float sb[8];
    int i = blockIdx.x;
    size_t ib = (size_t)i * C1;
    float d0 = dist[ib];
    const unsigned char* Kr = K + (size_t)i * CPB;
    float num = 0, den = 0;
    for (int j0 = threadIdx.x * 4; j0 < C1; j0 += 1024) {
        int p = *reinterpret_cast<const int*>(Kr + j0);
#pragma unroll
        for (int k = 0; k < 4; ++k) {
            int j = j0 + k;
            int jc = (j < C1) ? j : (C1 - 1);
            float kv = fp8_to_f(p >> (k * 8)) * v[jc];   // K pad = 0 -> kv = 0 beyond C1
            float g = gm_label(dist[ib + jc] - d0, lab[ib + jc]);
            den += kv;
            num = fmaf(g, kv, num);
        }
    }
    float2 r = block_reduce_2(num, den, sb);
    if (threadIdx.x == 0) ratio[i] = r.x / r.y;
}

__global__ __launch_bounds__(256) void loss2_k(const unsigned char* __restrict__ K,
                                               const float* __restrict__ v,
                                               const float* __restrict__ dist,
                                               const float* __restrict__ dcol,
                                               float* __restrict__ ratio) {
    __shared__ float sb[8];
    int i = blockIdx.x;
    const unsigned char* Kr = K + (size_t)i * CPB;
    const float* Dr = dist + (size_t)i * C1 + 21;
    float num = 0, den = 0;
    for (int j0 = threadIdx.x * 4; j0 < C2; j0 += 1024) {
        int p = *reinterpret_cast<const int*>(Kr + j0);
#pragma unroll
        for (int k = 0; k < 4; ++k) {
            int j = j0 + k;
            if (j == i) continue;
            float kv = fp8_to_f(p >> (k * 8)) * v[j];
            float h = fmaxf(0.09f + Dr[j] - dcol[j], 0.0f);
            den += kv;
            num = fmaf(h, kv, num);
        }
    }
    float2 r = block_reduce_2(num, den, sb);
    if (threadIdx.x == 0) ratio[i] = r.x / r.y;
}

__global__ __launch_bounds__(256) void final_k(const float* __restrict__ r1,
                                               const float* __restrict__ r2,
                                               float* __restrict__ out) {
    __shared__ float sb[8];
    float s1 = 0, s2 = 0;
    for (int i = threadIdx.x; i < R; i += 256) { s1 += r1[i]; s2 += r2[i]; }
    float2 t = block_reduce_2(s1, s2, sb);
    if (threadIdx.x == 0)
        out[0] = t.x / ((float)R * (float)C1) + t.y / ((float)R * (float)C2);
}

extern "C" void kernel_launch(void* const* d_in, const int* in_sizes, int n_in,
                              void* d_out, int out_size, void* d_ws, size_t ws_size,
                              hipStream_t stream) {
    const float* dist = (const float*)d_in[0];
    const int* lab = (const int*)d_in[1];
    float* out = (float*)d_out;
    char* ws = (char*)d_ws;

    size_t need = (size_t)R * CPB                        // K (fp8)
                + (size_t)NBLK * CPF * sizeof(float)     // part
                + (size_t)CPF * sizeof(float)            // v
                + 3 * (size_t)R * sizeof(float)          // dcol, rat1, rat2
                + 72 * 256;                              // barrier lines
    if (ws_size < need) return;

    size_t off = 0;
    unsigned char* K = (unsigned char*)(ws + off); off += (size_t)R * CPB;
    float* part = (float*)(ws + off);  off += (size_t)NBLK * CPF * sizeof(float);
    float* v = (float*)(ws + off);     off += (size_t)CPF * sizeof(float);
    float* dcol = (float*)(ws + off);  off += (size_t)R * sizeof(float);
    float* rat1 = (float*)(ws + off);  off += (size_t)R * sizeof(float);
    float* rat2 = (float*)(ws + off);  off += (size_t)R * sizeof(float);
    unsigned* bar = (unsigned*)(ws + off); off += 72 * 256;
    unsigned* ctr = bar;              // 8 lines
    unsigned* ep  = bar + 8 * 64;     // 64 lines

    float aval = 1.0f / (float)R;
    int gb = (CPB / 4 + 255) / 256;   // 9 blocks per row

    // ---- phase 1 ----
    build_k1<<<dim3(gb, R), 256, 0, stream>>>(dist, lab, K);
    zero_bar<<<dim3(1), 128, 0, stream>>>(bar);
    sink_k<<<dim3(NBLK), TPB, 0, stream>>>(K, part, v, ctr, ep, C1, aval, 1.0f / (float)C1);
    loss1_k<<<dim3(R), 256, 0, stream>>>(K, v, dist, lab, rat1);

    // ---- phase 2 (reuses K buffer) ----
    diag_k<<<dim3(R / 256), 256, 0, stream>>>(dist, dcol);
    build_k2<<<dim3(gb, R), 256, 0, stream>>>(dist, dcol, K);
    zero_bar<<<dim3(1), 128, 0, stream>>>(bar);
    sink_k<<<dim3(NBLK), TPB, 0, stream>>>(K, part, v, ctr, ep, C2, aval, 1.0f / (float)C2);
    loss2_k<<<dim3(R), 256, 0, stream>>>(K, v, dist, dcol, rat2);

    final_k<<<dim3(1), 256, 0, stream>>>(rat1, rat2, out);
}

// Round 8
// 10292.271 us; speedup vs baseline: 1.5823x; 1.2373x over previous
//
#include <hip/hip_runtime.h>

#define R     8192
#define C1    8213
#define C2    8192
#define KROW  8224      // K row stride in BYTES (514 x 16B chunks, zero-padded)
#define TROW  8192      // KT row stride in BYTES (512 x 16B chunks)
#define NKC   514
#define NTC   512
#define NBLK  512       // persistent grid (2 blocks/CU by capacity)
#define TPB   512
#define CPF   8224      // v length in floats

typedef float f32x2 __attribute__((ext_vector_type(2)));

__device__ __forceinline__ void fp8x16_to_f(const int4 w, float f[16]) {
    f32x2 p;
    p = __builtin_amdgcn_cvt_pk_f32_fp8(w.x, false); f[0]  = p.x; f[1]  = p.y;
    p = __builtin_amdgcn_cvt_pk_f32_fp8(w.x, true);  f[2]  = p.x; f[3]  = p.y;
    p = __builtin_amdgcn_cvt_pk_f32_fp8(w.y, false); f[4]  = p.x; f[5]  = p.y;
    p = __builtin_amdgcn_cvt_pk_f32_fp8(w.y, true);  f[6]  = p.x; f[7]  = p.y;
    p = __builtin_amdgcn_cvt_pk_f32_fp8(w.z, false); f[8]  = p.x; f[9]  = p.y;
    p = __builtin_amdgcn_cvt_pk_f32_fp8(w.z, true);  f[10] = p.x; f[11] = p.y;
    p = __builtin_amdgcn_cvt_pk_f32_fp8(w.w, false); f[12] = p.x; f[13] = p.y;
    p = __builtin_amdgcn_cvt_pk_f32_fp8(w.w, true);  f[14] = p.x; f[15] = p.y;
}

__device__ __forceinline__ float fp8_to_f(int byte) {
    f32x2 p = __builtin_amdgcn_cvt_pk_f32_fp8(byte & 0xff, false);
    return p.x;
}

__device__ __forceinline__ float gm_label(float sc, int lab) {
    if (lab == 0) return fmaxf(-0.02f - sc, 0.0f) + fmaxf(sc, 0.0f);
    if (lab == 3) return fmaxf(0.09f + sc, 0.0f);
    return fmaxf(0.05f + sc, 0.0f) + fmaxf(-0.09f - sc, 0.0f); // labels 1|2
}

__device__ __forceinline__ float kval(float gm) {
    // K = exp(-M/REG), M = exp(-GM), REG = -0.2 -> exp(5*exp(-GM)); hw exp
    return __expf(5.0f * __expf(-gm));
}

__device__ __forceinline__ void load_w16(const float4* __restrict__ p4, int ch, float w[16]) {
    float4 q0 = p4[ch * 4], q1 = p4[ch * 4 + 1];
    float4 q2 = p4[ch * 4 + 2], q3 = p4[ch * 4 + 3];
    w[0] = q0.x;  w[1] = q0.y;  w[2]  = q0.z;  w[3]  = q0.w;
    w[4] = q1.x;  w[5] = q1.y;  w[6]  = q1.z;  w[7]  = q1.w;
    w[8] = q2.x;  w[9] = q2.y;  w[10] = q2.z;  w[11] = q2.w;
    w[12] = q3.x; w[13] = q3.y; w[14] = q3.z; w[15] = q3.w;
}

__device__ __forceinline__ float dot16(const float f[16], const float w[16]) {
    float d = 0.0f;
#pragma unroll
    for (int k = 0; k < 16; ++k) d = fmaf(f[k], w[k], d);
    return d;
}

// ---- build kernels (R5-proven) ----

__global__ __launch_bounds__(256) void build_k1(const float* __restrict__ dist,
                                                const int* __restrict__ lab,
                                                unsigned char* __restrict__ K) {
    int row = blockIdx.y;
    int j0 = (blockIdx.x * 256 + threadIdx.x) * 4;
    if (j0 >= KROW) return;
    size_t ib = (size_t)row * C1;
    float d0 = dist[ib];
    float val[4];
#pragma unroll
    for (int k = 0; k < 4; ++k) {
        int j = j0 + k;
        val[k] = 0.0f;
        if (j < C1) {
            float g = gm_label(dist[ib + j] - d0, lab[ib + j]);
            val[k] = kval(g);
        }
    }
    int p = 0;
    p = __builtin_amdgcn_cvt_pk_fp8_f32(val[0], val[1], p, false);
    p = __builtin_amdgcn_cvt_pk_fp8_f32(val[2], val[3], p, true);
    *reinterpret_cast<int*>(K + (size_t)row * KROW + j0) = p;
}

__global__ __launch_bounds__(256) void diag_k(const float* __restrict__ dist,
                                              float* __restrict__ dcol) {
    int j = blockIdx.x * 256 + threadIdx.x;
    if (j < R) dcol[j] = dist[(size_t)j * C1 + 21 + j];
}

__global__ __launch_bounds__(256) void build_k2(const float* __restrict__ dist,
                                                const float* __restrict__ dcol,
                                                unsigned char* __restrict__ K) {
    int row = blockIdx.y;
    int j0 = (blockIdx.x * 256 + threadIdx.x) * 4;
    if (j0 >= KROW) return;
    size_t ib = (size_t)row * C1 + 21;
    float val[4];
#pragma unroll
    for (int k = 0; k < 4; ++k) {
        int j = j0 + k;
        val[k] = 0.0f;
        if (j < C2) {
            float s = dist[ib + j] - dcol[j];
            float g = (j == row) ? 0.0f : fmaxf(0.09f + s, 0.0f);
            val[k] = kval(g);
        }
    }
    int p = 0;
    p = __builtin_amdgcn_cvt_pk_fp8_f32(val[0], val[1], p, false);
    p = __builtin_amdgcn_cvt_pk_fp8_f32(val[2], val[3], p, true);
    *reinterpret_cast<int*>(K + (size_t)row * KROW + j0) = p;
}

// ---- byte transpose K[8192][KROW] -> KT[8224][TROW] via 64x64 LDS tile ----
__global__ __launch_bounds__(256) void transpose_k(const unsigned char* __restrict__ K,
                                                   unsigned char* __restrict__ KT) {
    __shared__ unsigned char tile[64][64];
    int i0 = blockIdx.x * 64;   // K row block
    int j0 = blockIdx.y * 64;   // K col block (may overhang past 8224)
    int t = threadIdx.x;
    int r = t >> 2, cb = (t & 3) << 4;
    if (j0 + cb < KROW) {
        int4 w = *reinterpret_cast<const int4*>(K + (size_t)(i0 + r) * KROW + j0 + cb);
        *reinterpret_cast<int4*>(&tile[r][cb]) = w;
    }
    __syncthreads();
    int jl = t >> 2, ib = (t & 3) << 4;
    if (j0 + jl < KROW) {
        unsigned char tmp[16];
#pragma unroll
        for (int k = 0; k < 16; ++k) tmp[k] = tile[ib + k][jl];
        *reinterpret_cast<int4*>(KT + (size_t)(j0 + jl) * TROW + i0 + ib) =
            *reinterpret_cast<const int4*>(tmp);
    }
}

// ---- barrier: 64 arrival lines + wave-parallel aggregate + 64 epoch lines ----

__global__ void zero_bar(unsigned* __restrict__ bar) {
    int i = threadIdx.x;
    if (i < 128) bar[i << 6] = 0u;
}

__device__ __forceinline__ void gridbar(unsigned* __restrict__ ctr,
                                        unsigned* __restrict__ ep,
                                        int b, unsigned k) {
    __syncthreads();
    if (threadIdx.x == 0)
        __hip_atomic_fetch_add(&ctr[(b & 63) << 6], 1u, __ATOMIC_RELEASE,
                               __HIP_MEMORY_SCOPE_AGENT);
    if (b == 0) {
        if (threadIdx.x < 64) {
            int l = threadIdx.x;
            const unsigned target = k * (unsigned)NBLK;
            for (;;) {
                unsigned s = __hip_atomic_load(&ctr[l << 6], __ATOMIC_ACQUIRE,
                                               __HIP_MEMORY_SCOPE_AGENT);
#pragma unroll
                for (int off = 32; off; off >>= 1) s += __shfl_down(s, off, 64);
                s = __shfl(s, 0, 64);
                if (s >= target) break;
                __builtin_amdgcn_s_sleep(1);
            }
            __hip_atomic_store(&ep[l << 6], k, __ATOMIC_RELEASE,
                               __HIP_MEMORY_SCOPE_AGENT);
        }
    } else {
        if (threadIdx.x == 0) {
            unsigned* my = &ep[(b & 63) << 6];
            while (__hip_atomic_load(my, __ATOMIC_ACQUIRE,
                                     __HIP_MEMORY_SCOPE_AGENT) < k)
                __builtin_amdgcn_s_sleep(2);
        }
    }
    __syncthreads();
}

// ---- persistent Sinkhorn: colphase (KT row-dots -> v), barrier, rowphase
//      (K row-dots -> u), barrier. All dots wave-local; no part buffer. ----
__global__ __launch_bounds__(TPB, 4) void sink_k(const unsigned char* __restrict__ K,
                                                 const unsigned char* __restrict__ KT,
                                                 float* __restrict__ u,
                                                 float* __restrict__ v,
                                                 unsigned* __restrict__ ctr,
                                                 unsigned* __restrict__ ep,
                                                 int C, float aval, float bval) {
    __shared__ float sp[8];
    const int tx = threadIdx.x, b = blockIdx.x;
    const int lane = tx & 63, wv = tx >> 6;
    const int4* Kb = reinterpret_cast<const int4*>(K);
    const int4* KTb = reinterpret_cast<const int4*>(KT);
    const float4* u4 = reinterpret_cast<const float4*>(u);
    const float4* v4 = reinterpret_cast<const float4*>(v);
    const bool isSpec = (b & 15) == 0;
    const int je = 8192 + (b >> 4);
    unsigned bark = 0;

    for (int t = 0; t < 50; ++t) {
        // ---- column phase: v[j] = bval / (KT[j] . u); u uniform at t=0 ----
        {
            int ja = b * 16 + 2 * wv, jb = ja + 1;
            const int4* Ka = KTb + (size_t)ja * NTC;
            const int4* Kc = KTb + (size_t)jb * NTC;
            float da = 0.0f, db = 0.0f;
            if (t == 0) {
                for (int s = 0; s < 8; ++s) {
                    int ch = s * 64 + lane;
                    float f[16];
                    fp8x16_to_f(Ka[ch], f);
#pragma unroll
                    for (int k = 0; k < 16; ++k) da += f[k];
                    fp8x16_to_f(Kc[ch], f);
#pragma unroll
                    for (int k = 0; k < 16; ++k) db += f[k];
                }
                da *= aval; db *= aval;
            } else {
                for (int s = 0; s < 8; ++s) {
                    int ch = s * 64 + lane;
                    float w[16];
                    load_w16(u4, ch, w);
                    float f[16];
                    fp8x16_to_f(Ka[ch], f);
                    da += dot16(f, w);
                    fp8x16_to_f(Kc[ch], f);
                    db += dot16(f, w);
                }
            }
#pragma unroll
            for (int off = 32; off; off >>= 1) {
                da += __shfl_down(da, off, 64);
                db += __shfl_down(db, off, 64);
            }
            if (lane == 0) {
                v[ja] = (ja < C) ? bval / da : 0.0f;
                v[jb] = (jb < C) ? bval / db : 0.0f;
            }
            if (isSpec) {
                // extra col je: wave wv handles chunks wv*64+lane (1/lane)
                const int4* Ke = KTb + (size_t)je * NTC;
                int ch = (wv << 6) | lane;
                float f[16];
                fp8x16_to_f(Ke[ch], f);
                float de = 0.0f;
                if (t == 0) {
#pragma unroll
                    for (int k = 0; k < 16; ++k) de += f[k];
                } else {
                    float w[16];
                    load_w16(u4, ch, w);
                    de = dot16(f, w);
                }
#pragma unroll
                for (int off = 32; off; off >>= 1) de += __shfl_down(de, off, 64);
                if (lane == 0) sp[wv] = de;
                __syncthreads();
                if (tx == 0) {
                    float s = sp[0] + sp[1] + sp[2] + sp[3]
                            + sp[4] + sp[5] + sp[6] + sp[7];
                    if (t == 0) s *= aval;
                    v[je] = (je < C) ? bval / s : 0.0f;
                }
            }
        }
        gridbar(ctr, ep, b, ++bark);
        if (t == 49) break;

        // ---- row phase: u[i] = aval / (K[i] . v) ----
        {
            int ra = b * 16 + 2 * wv, rb = ra + 1;
            const int4* Ka = Kb + (size_t)ra * NKC;
            const int4* Kc = Kb + (size_t)rb * NKC;
            float da = 0.0f, db = 0.0f;
            for (int s = 0; s < 8; ++s) {
                int ch = s * 64 + lane;
                float w[16];
                load_w16(v4, ch, w);
                float f[16];
                fp8x16_to_f(Ka[ch], f);
                da += dot16(f, w);
                fp8x16_to_f(Kc[ch], f);
                db += dot16(f, w);
            }
            if (lane < 2) {
                int ch = 512 + lane;
                float w[16];
                load_w16(v4, ch, w);
                float f[16];
                fp8x16_to_f(Ka[ch], f);
                da += dot16(f, w);
                fp8x16_to_f(Kc[ch], f);
                db += dot16(f, w);
            }
#pragma unroll
            for (int off = 32; off; off >>= 1) {
                da += __shfl_down(da, off, 64);
                db += __shfl_down(db, off, 64);
            }
            if (lane == 0) {
                u[ra] = aval / da;
                u[rb] = aval / db;
            }
        }
        gridbar(ctr, ep, b, ++bark);
    }
}

// ---- loss reductions (R5-proven) ----

__device__ __forceinline__ float2 block_reduce_2(float x, float y, float* sb) {
#pragma unroll
    for (int off = 32; off; off >>= 1) {
        x += __shfl_down(x, off, 64);
        y += __shfl_down(y, off, 64);
    }
    if ((threadIdx.x & 63) == 0) {
        int w = threadIdx.x >> 6;
        sb[w] = x; sb[4 + w] = y;
    }
    __syncthreads();
    float2 r;
    r.x = sb[0] + sb[1] + sb[2] + sb[3];
    r.y = sb[4] + sb[5] + sb[6] + sb[7];
    __syncthreads();
    return r;
}

__global__ __launch_bounds__(256) void loss1_k(const unsigned char* __restrict__ K,
                                               const float* __restrict__ v,
                                               const float* __restrict__ dist,
                                               const int* __restrict__ lab,
                                               float* __restrict__ ratio) {
    __shared__ float sb[8];
    int i = blockIdx.x;
    size_t ib = (size_t)i * C1;
    float d0 = dist[ib];
    const unsigned char* Kr = K + (size_t)i * KROW;
    float num = 0, den = 0;
    for (int j0 = threadIdx.x * 4; j0 < C1; j0 += 1024) {
        int p = *reinterpret_cast<const int*>(Kr + j0);
#pragma unroll
        for (int k = 0; k < 4; ++k) {
            int j = j0 + k;
            int jc = (j < C1) ? j : (C1 - 1);
            float kv = fp8_to_f(p >> (k * 8)) * v[jc];   // K pad = 0 -> kv = 0 beyond C1
            float g = gm_label(dist[ib + jc] - d0, lab[ib + jc]);
            den += kv;
            num = fmaf(g, kv, num);
        }
    }
    float2 r = block_reduce_2(num, den, sb);
    if (threadIdx.x == 0) ratio[i] = r.x / r.y;
}

__global__ __launch_bounds__(256) void loss2_k(const unsigned char* __restrict__ K,
                                               const float* __restrict__ v,
                                               const float* __restrict__ dist,
                                               const float* __restrict__ dcol,
                                               float* __restrict__ ratio) {
    __shared__ float sb[8];
    int i = blockIdx.x;
    const unsigned char* Kr = K + (size_t)i * KROW;
    const float* Dr = dist + (size_t)i * C1 + 21;
    float num = 0, den = 0;
    for (int j0 = threadIdx.x * 4; j0 < C2; j0 += 1024) {
        int p = *reinterpret_cast<const int*>(Kr + j0);
#pragma unroll
        for (int k = 0; k < 4; ++k) {
            int j = j0 + k;
            if (j == i) continue;
            float kv = fp8_to_f(p >> (k * 8)) * v[j];
            float h = fmaxf(0.09f + Dr[j] - dcol[j], 0.0f);
            den += kv;
            num = fmaf(h, kv, num);
        }
    }
    float2 r = block_reduce_2(num, den, sb);
    if (threadIdx.x == 0) ratio[i] = r.x / r.y;
}

__global__ __launch_bounds__(256) void final_k(const float* __restrict__ r1,
                                               const float* __restrict__ r2,
                                               float* __restrict__ out) {
    __shared__ float sb[8];
    float s1 = 0, s2 = 0;
    for (int i = threadIdx.x; i < R; i += 256) { s1 += r1[i]; s2 += r2[i]; }
    float2 t = block_reduce_2(s1, s2, sb);
    if (threadIdx.x == 0)
        out[0] = t.x / ((float)R * (float)C1) + t.y / ((float)R * (float)C2);
}

extern "C" void kernel_launch(void* const* d_in, const int* in_sizes, int n_in,
                              void* d_out, int out_size, void* d_ws, size_t ws_size,
                              hipStream_t stream) {
    const float* dist = (const float*)d_in[0];
    const int* lab = (const int*)d_in[1];
    float* out = (float*)d_out;
    char* ws = (char*)d_ws;

    size_t need = (size_t)R * KROW                       // K (fp8)
                + (size_t)KROW * TROW                    // KT (fp8)
                + (size_t)CPF * sizeof(float)            // v
                + 4 * (size_t)R * sizeof(float)          // u, dcol, rat1, rat2
                + 128 * 256;                             // barrier lines
    if (ws_size < need) return;

    size_t off = 0;
    unsigned char* K = (unsigned char*)(ws + off);  off += (size_t)R * KROW;
    unsigned char* KT = (unsigned char*)(ws + off); off += (size_t)KROW * TROW;
    float* v = (float*)(ws + off);     off += (size_t)CPF * sizeof(float);
    float* u = (float*)(ws + off);     off += (size_t)R * sizeof(float);
    float* dcol = (float*)(ws + off);  off += (size_t)R * sizeof(float);
    float* rat1 = (float*)(ws + off);  off += (size_t)R * sizeof(float);
    float* rat2 = (float*)(ws + off);  off += (size_t)R * sizeof(float);
    unsigned* bar = (unsigned*)(ws + off); off += 128 * 256;
    unsigned* ctr = bar;              // 64 lines
    unsigned* epb = bar + 64 * 64;    // 64 lines

    float aval = 1.0f / (float)R;
    int gb = (KROW / 4 + 255) / 256;   // 9 blocks per row

    // ---- phase 1 ----
    build_k1<<<dim3(gb, R), 256, 0, stream>>>(dist, lab, K);
    transpose_k<<<dim3(R / 64, (KROW + 63) / 64), 256, 0, stream>>>(K, KT);
    zero_bar<<<dim3(1), 128, 0, stream>>>(bar);
    sink_k<<<dim3(NBLK), TPB, 0, stream>>>(K, KT, u, v, ctr, epb, C1, aval,
                                           1.0f / (float)C1);
    loss1_k<<<dim3(R), 256, 0, stream>>>(K, v, dist, lab, rat1);

    // ---- phase 2 (reuses K and KT buffers) ----
    diag_k<<<dim3(R / 256), 256, 0, stream>>>(dist, dcol);
    build_k2<<<dim3(gb, R), 256, 0, stream>>>(dist, dcol, K);
    transpose_k<<<dim3(R / 64, (KROW + 63) / 64), 256, 0, stream>>>(K, KT);
    zero_bar<<<dim3(1), 128, 0, stream>>>(bar);
    sink_k<<<dim3(NBLK), TPB, 0, stream>>>(K, KT, u, v, ctr, epb, C2, aval,
                                           1.0f / (float)C2);
    loss2_k<<<dim3(R), 256, 0, stream>>>(K, v, dist, dcol, rat2);

    final_k<<<dim3(1), 256, 0, stream>>>(rat1, rat2, out);
}